// Round 12
// baseline (521.442 us; speedup 1.0000x reference)
//
#include <hip/hip_runtime.h>

// HierarchicalSoftmax: out[b, c*320 + t] = (x_b · topW[:,c] + top_b[c]) + (x_b · botW[t,:] + bot_b[t])
// B=1024, NHID=128, NCLASSES=320, PER_CLASS=320, row = 102400 fp32, out = 419.4 MB.
//
// Ledger (kernel = dur - ~272 fill): R0 fused+nt 447 | R1 fused 442 | R4 defused 458 |
//   R7 defused+nt 463 | R8 fill-mimic-1024-wave 450  => kernel ~170-195 us (~2.4 TB/s,
//   ~3.9 B/cyc/CU) across FIVE disjoint structures; fill does 10.2 B/cyc/CU on same buffer.
//   Exonerated: fusion/barriers, nt, RFO, address pattern, occupancy, inner-loop dep shape.
//
// R9-R12 = DIAGNOSTIC ROUND (intentional ~2x slowdown): K2 writes the output TWICE (idempotent)
// to push its dispatch past the ~270 us fills into rocprof top-5, giving first DIRECT counters:
//   a) intrinsic ceiling: dur ~630, K2 row WRITE~819200KB, FETCH small -> read VALUBusy/Occ.
//   b) hidden fixed graph cost H: dur ~270+H+10+2*(175-H) < 630 -> kernel was never the problem.
//   c) first-touch/TLB: 2nd pass at fill speed -> K2~245, dur ~525.
//   d) hidden read-allocate: K2 FETCH ~400MB -> attack with MUBUF sc1/nt asm stores.
// (R12: fourth submission attempt — three acquisition timeouts; never measured.)

#define BATCH      1024
#define NHID       128
#define NCLASSES   320
#define PER_CLASS  320
#define ROW_ELEMS  (NCLASSES * PER_CLASS)    // 102400
#define ROW_F4     (ROW_ELEMS / 4)           // 25600
#define PC_F4      (PER_CLASS / 4)           // 80
#define LPR        (NCLASSES + PER_CLASS)    // 640 logits per row
#define LPR_F4     (LPR / 4)                 // 160
#define WS_BYTES   ((size_t)BATCH * LPR * sizeof(float))  // 2.62 MB

#define K2_BLOCKS  256
#define K2_THREADS 256
#define RPB        (BATCH / K2_BLOCKS)       // 4 rows per block == waves per block
#define ITERS_PW   (ROW_F4 / 64)             // 400 f32x4 stores per wave (per row)

typedef float f32x4 __attribute__((ext_vector_type(4)));

// ---------------- K1: logits -> ws[b*640 + {c | 320+t}] ----------------
__global__ __launch_bounds__(LPR) void hs_logits_kernel(
    const float* __restrict__ inputs,     // [B, NHID]
    const float* __restrict__ top_W,      // [NHID, NCLASSES] (k-major)
    const float* __restrict__ top_b,      // [NCLASSES]
    const float* __restrict__ bottom_W,   // [PER_CLASS, NHID]
    const float* __restrict__ bottom_b,   // [PER_CLASS]
    float* __restrict__ ws)               // [B, 640]
{
    __shared__ __align__(16) float s_in[NHID];
    const int b   = blockIdx.x;
    const int tid = threadIdx.x;          // 0..639, exactly one dot each

    if (tid < NHID) s_in[tid] = inputs[b * NHID + tid];
    __syncthreads();

    float acc;
    if (tid < NCLASSES) {
        acc = top_b[tid];
        #pragma unroll 8
        for (int k = 0; k < NHID; ++k)
            acc += s_in[k] * top_W[k * NCLASSES + tid];      // coalesced across tid
    } else {
        const int t = tid - NCLASSES;
        acc = bottom_b[t];
        const f32x4* w4 = (const f32x4*)(bottom_W + t * NHID);
        #pragma unroll 8
        for (int k4 = 0; k4 < NHID / 4; ++k4) {
            f32x4 w = w4[k4];
            acc += s_in[4*k4+0]*w.x + s_in[4*k4+1]*w.y
                 + s_in[4*k4+2]*w.z + s_in[4*k4+3]*w.w;
        }
    }
    ws[b * LPR + tid] = acc;
}

// ---------------- K2 DIAG: R8 stream x2 passes (idempotent rewrite) ----------------
__global__ __launch_bounds__(K2_THREADS) void hs_stream_kernel(
    const float* __restrict__ ws,         // [B, 640]
    float* __restrict__ out)
{
    __shared__ __align__(16) float s_log[RPB][LPR];   // 4 x 640 x 4B = 10.24 KB

    const int b   = blockIdx.x;
    const int tid = threadIdx.x;

    const f32x4* wsrc = (const f32x4*)(ws + (size_t)b * RPB * LPR);
    f32x4* sdst = (f32x4*)&s_log[0][0];
    for (int j = tid; j < RPB * LPR_F4; j += K2_THREADS)
        sdst[j] = wsrc[j];
    __syncthreads();

    const int w    = tid >> 6;            // wave id 0..3 -> row
    const int lane = tid & 63;
    const float* srow  = s_log[w];                        // 640 logits for this row
    const f32x4* srow4 = (const f32x4*)(srow + NCLASSES); // bottom 320 as 80 f32x4
    f32x4* outp = (f32x4*)out + (size_t)(b * RPB + w) * ROW_F4;

    // TWO identical passes over this wave's 409.6 KB region. Same thread writes same value
    // to same address in both passes -> final contents identical to single-pass (correct).
    // Purpose: lift this dispatch above the 270us fills so rocprof top-5 shows its counters.
    for (int pass = 0; pass < 2; ++pass) {
        #pragma unroll 8
        for (int it = 0; it < ITERS_PW; ++it) {
            const unsigned g  = lane + it * 64;      // 0..25599, wave-sequential
            const unsigned c  = g / PC_F4;           // magic mul
            const unsigned t4 = g - c * PC_F4;
            const float tv = srow[c];                // ds_read_b32 broadcast
            const f32x4 bv = srow4[t4];              // ds_read_b128, conflict-free
            f32x4 v;
            v.x = tv + bv.x;
            v.y = tv + bv.y;
            v.z = tv + bv.z;
            v.w = tv + bv.w;
            outp[g] = v;                             // 1KB/wave/iter, sequential cursor
        }
    }
}

// ---------------- fallback (R1 fused kernel) if ws unavailable ----------------
#define HALVES      2
#define CLS_PER_BLK (NCLASSES / HALVES)
#define FTHREADS    320
#define C_PER_ITER  (FTHREADS / PC_F4)
#define NITER       (CLS_PER_BLK / C_PER_ITER)

__global__ __launch_bounds__(FTHREADS) void hs_fused_kernel(
    const float* __restrict__ inputs, const float* __restrict__ top_W,
    const float* __restrict__ top_b, const float* __restrict__ bottom_W,
    const float* __restrict__ bottom_b, float* __restrict__ out)
{
    __shared__ __align__(16) float s_in[NHID];
    __shared__ float s_top[CLS_PER_BLK];
    __shared__ __align__(16) float s_bot[PER_CLASS];
    const int b = blockIdx.x, h = blockIdx.y, tid = threadIdx.x;
    if (tid < NHID) s_in[tid] = inputs[b * NHID + tid];
    __syncthreads();
    for (int j = tid; j < CLS_PER_BLK + PER_CLASS; j += FTHREADS) {
        float acc;
        if (j < CLS_PER_BLK) {
            const int c = h * CLS_PER_BLK + j;
            acc = top_b[c];
            #pragma unroll 8
            for (int k = 0; k < NHID; ++k) acc += s_in[k] * top_W[k * NCLASSES + c];
            s_top[j] = acc;
        } else {
            const int t = j - CLS_PER_BLK;
            acc = bottom_b[t];
            const f32x4* w4 = (const f32x4*)(bottom_W + t * NHID);
            #pragma unroll 8
            for (int k4 = 0; k4 < NHID / 4; ++k4) {
                f32x4 w = w4[k4];
                acc += s_in[4*k4+0]*w.x + s_in[4*k4+1]*w.y + s_in[4*k4+2]*w.z + s_in[4*k4+3]*w.w;
            }
            s_bot[t] = acc;
        }
    }
    __syncthreads();
    const int c_off = tid / PC_F4;
    const int t4    = tid - c_off * PC_F4;
    const f32x4 bv  = ((const f32x4*)s_bot)[t4];
    f32x4* outp = (f32x4*)out + (size_t)b * ROW_F4 + h * (CLS_PER_BLK * PC_F4) + c_off * PC_F4 + t4;
    #pragma unroll 8
    for (int it = 0; it < NITER; ++it) {
        const float tv = s_top[it * C_PER_ITER + c_off];
        f32x4 v;
        v.x = tv + bv.x; v.y = tv + bv.y; v.z = tv + bv.z; v.w = tv + bv.w;
        outp[it * (C_PER_ITER * PC_F4)] = v;
    }
}

extern "C" void kernel_launch(void* const* d_in, const int* in_sizes, int n_in,
                              void* d_out, int out_size, void* d_ws, size_t ws_size,
                              hipStream_t stream) {
    const float* inputs   = (const float*)d_in[0];
    const float* top_W    = (const float*)d_in[1];
    const float* top_b    = (const float*)d_in[2];
    const float* bottom_W = (const float*)d_in[3];
    const float* bottom_b = (const float*)d_in[4];
    float* out = (float*)d_out;

    if (d_ws != nullptr && ws_size >= WS_BYTES) {
        float* ws = (float*)d_ws;
        hs_logits_kernel<<<BATCH, LPR, 0, stream>>>(inputs, top_W, top_b, bottom_W, bottom_b, ws);
        hs_stream_kernel<<<K2_BLOCKS, K2_THREADS, 0, stream>>>(ws, out);
    } else {
        hs_fused_kernel<<<dim3(BATCH, HALVES), FTHREADS, 0, stream>>>(
            inputs, top_W, top_b, bottom_W, bottom_b, out);
    }
}